// Round 1
// baseline (678.506 us; speedup 1.0000x reference)
//
#include <hip/hip_runtime.h>

#define Bsz 1024
#define Tt  256
#define Vv  32004
#define Dd  50
#define Hh  64
#define RR  32   // vocab rows per build_tables block
#define RPB 16   // batch rows per lstm_main block

typedef __bf16 b16x8 __attribute__((ext_vector_type(8)));
typedef __bf16 b16x4 __attribute__((ext_vector_type(4)));
typedef float  f32x4 __attribute__((ext_vector_type(4)));

// barrier WITHOUT vmcnt(0) drain: LDS ordering only, in-flight global loads
// (the xw register prefetch) survive across it.
__device__ __forceinline__ void barrier_novm() {
    asm volatile("s_waitcnt lgkmcnt(0)\n\ts_barrier" ::: "memory");
}
__device__ __forceinline__ float fsig(float x) {
    return __fdividef(1.0f, 1.0f + __expf(-x));
}
__device__ __forceinline__ float ftanh(float x) {
    return 2.0f * __fdividef(1.0f, 1.0f + __expf(-2.0f * x)) - 1.0f;
}

// ---------------------------------------------------------------------------
// Prologue: tab[v][g] = sum_d emb[v][d] * Wih[g][d] + bih[g] + bhh[g]
// v2: W row kept in REGISTERS (it was written and read by the same thread via
// LDS before — pure LDS-pipe overhead, and 53KB LDS capped occupancy at
// 2 blocks/CU). Now LDS = 6.6KB emb tile only.
// ---------------------------------------------------------------------------
__launch_bounds__(256)
__global__ void build_tables(const float* __restrict__ emb,
                             const float* __restrict__ Wih1,
                             const float* __restrict__ bih1,
                             const float* __restrict__ bhh1,
                             const float* __restrict__ Wih2,
                             const float* __restrict__ bih2,
                             const float* __restrict__ bhh2,
                             float* __restrict__ tab1,
                             float* __restrict__ tab2) {
    const int v0 = blockIdx.x * RR;
    const int g  = threadIdx.x;
    const int nr = min(RR, Vv - v0);

    const float* Wih = blockIdx.y ? Wih2 : Wih1;
    const float* bih = blockIdx.y ? bih2 : bih1;
    const float* bhh = blockIdx.y ? bhh2 : bhh1;
    float*       tab = blockIdx.y ? tab2 : tab1;

    __shared__ __align__(16) float elds[RR * 52];

    // thread g's weight row (gate g), private -> registers
    float4 wreg[13];
    {
        const float* wrow = Wih + (size_t)g * Dd;
#pragma unroll
        for (int j = 0; j < 12; ++j) {
            const float2 a = *(const float2*)(wrow + 4 * j);
            const float2 b = *(const float2*)(wrow + 4 * j + 2);
            wreg[j] = make_float4(a.x, a.y, b.x, b.y);
        }
        const float2 t = *(const float2*)(wrow + 48);
        wreg[12] = make_float4(t.x, t.y, 0.0f, 0.0f);
    }
    for (int i = threadIdx.x; i < nr * 52; i += 256) {
        const int row = i / 52;
        const int col = i - row * 52;
        elds[i] = (col < Dd) ? emb[(size_t)(v0 + row) * Dd + col] : 0.0f;
    }
    __syncthreads();

    const float bias = bih[g] + bhh[g];

    for (int c = 0; c < RR / 8; ++c) {
        const int r0 = c * 8;
        float acc[8];
#pragma unroll
        for (int r = 0; r < 8; ++r) acc[r] = 0.0f;
#pragma unroll
        for (int j = 0; j < 13; ++j) {
            const float4 w = wreg[j];
#pragma unroll
            for (int r = 0; r < 8; ++r) {
                const float4 e = *(const float4*)(&elds[(r0 + r) * 52 + 4 * j]);
                acc[r] += e.x * w.x + e.y * w.y + e.z * w.z + e.w * w.w;
            }
        }
#pragma unroll
        for (int r = 0; r < 8; ++r) {
            const int row = r0 + r;
            if (row < nr)
                tab[(size_t)(v0 + row) * 256 + g] = acc[r] + bias;
        }
    }
}

// ---------------------------------------------------------------------------
// v2 recurrence: 64 blocks x 16 batch rows, 256 threads (4 waves).
// Wave w owns hidden units [16w,16w+16) for ALL 4 gate types: its 8 MFMAs are
// m-tiles {w,4+w,8+w,12+w} x 2 K-halves, B = h[64 x 16 rows] (all 16 columns
// real data now, was 4/16). C-fragment mapping (col=lane&15=batch row,
// row=4q+r=unit offset) leaves i,f,g,o of the lane's own 4 hidden units in its
// own acc registers -> gate update happens IN REGISTERS: no graw LDS
// round-trip, ONE barrier per step (double-buffered hsh: read buf t&1, write
// the other). xw enters as the MFMA C-operand (prefetched float4 per gate
// type, distance 4: Sa..Sd).
// ---------------------------------------------------------------------------
__launch_bounds__(256, 1)
__global__ void lstm_main(const int*   __restrict__ s1,
                          const int*   __restrict__ s2,
                          const int*   __restrict__ len1,
                          const int*   __restrict__ len2,
                          const float* __restrict__ tab1,
                          const float* __restrict__ tab2,
                          const float* __restrict__ Whh1,
                          const float* __restrict__ Whh2,
                          const float* __restrict__ Wl1,
                          const float* __restrict__ bl1,
                          const float* __restrict__ Wl2,
                          const float* __restrict__ bl2,
                          float* __restrict__ out) {
    const int tid  = threadIdx.x;
    const int w    = tid >> 6;        // wave id == hidden-unit slice [16w,16w+16)
    const int lane = tid & 63;
    const int q    = lane >> 4;       // MFMA quad
    const int mn   = lane & 15;       // batch row within block (B/C column)
    const int b0   = blockIdx.x * RPB;
    const int u0   = 16 * w + 4 * q;  // first hidden unit this lane updates

    __shared__ __align__(16) __bf16 hsh[2][RPB][72];  // h double-buffer (bf16)
    __shared__ int   toklds[RPB][Tt];                 // block's tokens, per phase
    __shared__ float h2s[RPB][64];
    __shared__ float ys[RPB][128];

    float c4[4]   = {0.0f, 0.0f, 0.0f, 0.0f};
    float selh[4] = {0.0f, 0.0f, 0.0f, 0.0f};
    float selc[4] = {0.0f, 0.0f, 0.0f, 0.0f};

    for (int phase = 0; phase < 2; ++phase) {
        const float* tab  = phase ? tab2 : tab1;
        const float* Whh  = phase ? Whh2 : Whh1;
        const int*   sent = phase ? s2 : s1;
        const int*   lenp = phase ? len2 : len1;

        // stage tokens: 16 rows x 256 steps (coalesced per row)
        for (int i = tid; i < RPB * Tt; i += 256)
            toklds[i >> 8][i & 255] = sent[(size_t)(b0 + (i >> 8)) * Tt + (i & 255)];

        // A fragments: A[m = mn][k = 8q + j] = Whh[64k + 16w + mn][...]
        b16x8 af[8];
#pragma unroll
        for (int k = 0; k < 4; ++k) {
            const int gate = 64 * k + 16 * w + mn;
#pragma unroll
            for (int kh = 0; kh < 2; ++kh) {
                const float* ar = Whh + (size_t)gate * Hh + kh * 32 + q * 8;
                const float4 f0 = *(const float4*)ar;
                const float4 f1 = *(const float4*)(ar + 4);
                b16x8 a;
                a[0] = (__bf16)f0.x; a[1] = (__bf16)f0.y;
                a[2] = (__bf16)f0.z; a[3] = (__bf16)f0.w;
                a[4] = (__bf16)f1.x; a[5] = (__bf16)f1.y;
                a[6] = (__bf16)f1.z; a[7] = (__bf16)f1.w;
                af[2 * k + kh] = a;
            }
        }

        // gather indices for this lane's 4 (row mn, unit u0+r) elements
        int mi4[4];
        {
            const int4 m4 = *(const int4*)(lenp + (size_t)(b0 + mn) * Hh + u0);
            mi4[0] = m4.x; mi4[1] = m4.y; mi4[2] = m4.z; mi4[3] = m4.w;
        }

        // seed h (zeros for phase 0, gathered state for phase 1) into buf 0
        b16x4 h0;
#pragma unroll
        for (int r = 0; r < 4; ++r) {
            const float hv = phase ? selh[r] : 0.0f;
            c4[r] = phase ? selc[r] : 0.0f;
            h0[r] = (__bf16)hv;
        }
        *(b16x4*)&hsh[0][mn][u0] = h0;
#pragma unroll
        for (int r = 0; r < 4; ++r) { selh[r] = 0.0f; selc[r] = 0.0f; }
        __syncthreads();

        // xw prefetch, distance 4. S[k][r] = tab[token][64k + u0 + r]
        f32x4 Sa[4], Sb[4], Sc[4], Sd[4];
        auto prime = [&](int t, f32x4 (&S)[4]) {
            const int tk = toklds[mn][t];
            const float* tp = tab + (size_t)tk * 256 + u0;
#pragma unroll
            for (int k = 0; k < 4; ++k) S[k] = *(const f32x4*)(tp + 64 * k);
        };
        prime(0, Sa); prime(1, Sb); prime(2, Sc); prime(3, Sd);

        auto step = [&](int t, f32x4 (&S)[4], int rb, int wb) {
            // B frags: B[k = 8q+j][n = mn] from hsh[rb][mn][...]
            const b16x8 bf0 = *(const b16x8*)&hsh[rb][mn][q * 8];
            const b16x8 bf1 = *(const b16x8*)&hsh[rb][mn][32 + q * 8];
            // token for the t+4 refill (issued with the B-frag reads)
            const int tn = t + 4;
            const int tk = toklds[mn][tn < Tt ? tn : Tt - 1];

            f32x4 acc[4];
#pragma unroll
            for (int k = 0; k < 4; ++k) {
                acc[k] = __builtin_amdgcn_mfma_f32_16x16x32_bf16(af[2 * k],     bf0, S[k],   0, 0, 0);
                acc[k] = __builtin_amdgcn_mfma_f32_16x16x32_bf16(af[2 * k + 1], bf1, acc[k], 0, 0, 0);
            }
            // refill S for t+4 (S consumed above as the MFMA C-operand)
            const float* tp = tab + (size_t)tk * 256 + u0;
#pragma unroll
            for (int k = 0; k < 4; ++k) S[k] = *(const f32x4*)(tp + 64 * k);

            // in-register update of this lane's 4 units (row mn)
            b16x4 hp;
#pragma unroll
            for (int r = 0; r < 4; ++r) {
                const float iv = fsig(acc[0][r]);
                const float fv = fsig(acc[1][r]);
                const float gv = ftanh(acc[2][r]);
                const float ov = fsig(acc[3][r]);
                c4[r] = fv * c4[r] + iv * gv;
                const float hv = ov * ftanh(c4[r]);
                if (t == mi4[r]) { selh[r] = hv; selc[r] = c4[r]; }
                hp[r] = (__bf16)hv;
            }
            *(b16x4*)&hsh[wb][mn][u0] = hp;
            barrier_novm();   // ONE barrier/step; global prefetch stays in flight
        };

        for (int t = 0; t < Tt; t += 4) {
            step(t,     Sa, 0, 1);
            step(t + 1, Sb, 1, 0);
            step(t + 2, Sc, 0, 1);
            step(t + 3, Sd, 1, 0);
        }
    }

    // ---------------- epilogue MLP on the 16 gathered rows ------------------
    {
        f32x4 sv;
        sv[0] = selh[0]; sv[1] = selh[1]; sv[2] = selh[2]; sv[3] = selh[3];
        *(f32x4*)&h2s[mn][u0] = sv;
    }
    __syncthreads();
#pragma unroll
    for (int p = 0; p < 8; ++p) {
        const int idx = tid + 256 * p;        // 2048 (row, neuron) tasks
        const int rr = idx >> 7, n = idx & 127;
        float a = bl1[n];
        const float* wl = Wl1 + n * 64;
#pragma unroll 8
        for (int k = 0; k < 64; ++k) a += h2s[rr][k] * wl[k];
        ys[rr][n] = ftanh(a);
    }
    __syncthreads();
    if (tid < 64) {
        const int rr = tid >> 2, o = tid & 3;
        float a = bl2[o];
        const float* wl = Wl2 + o * 128;
#pragma unroll 8
        for (int k = 0; k < 128; ++k) a += ys[rr][k] * wl[k];
        out[(size_t)(b0 + rr) * 4 + o] = a;
    }
}

// ---------------------------------------------------------------------------
extern "C" void kernel_launch(void* const* d_in, const int* in_sizes, int n_in,
                              void* d_out, int out_size, void* d_ws, size_t ws_size,
                              hipStream_t stream) {
    const int*   s1   = (const int*)d_in[0];
    const int*   s2   = (const int*)d_in[1];
    const int*   l1   = (const int*)d_in[2];
    const int*   l2   = (const int*)d_in[3];
    // d_in[4], d_in[5] (s1_s, s2_s) unused by the reference
    const float* emb  = (const float*)d_in[6];
    const float* Wih1 = (const float*)d_in[7];
    const float* Whh1 = (const float*)d_in[8];
    const float* bih1 = (const float*)d_in[9];
    const float* bhh1 = (const float*)d_in[10];
    const float* Wih2 = (const float*)d_in[11];
    const float* Whh2 = (const float*)d_in[12];
    const float* bih2 = (const float*)d_in[13];
    const float* bhh2 = (const float*)d_in[14];
    const float* Wl1  = (const float*)d_in[15];
    const float* bl1  = (const float*)d_in[16];
    const float* Wl2  = (const float*)d_in[17];
    const float* bl2  = (const float*)d_in[18];
    float* out = (float*)d_out;

    float* tab1 = (float*)d_ws;                       // [V,256] fp32
    float* tab2 = tab1 + (size_t)Vv * 256;            // [V,256] fp32  (65.6 MB)

    dim3 grid((Vv + RR - 1) / RR, 2);
    build_tables<<<grid, 256, 0, stream>>>(emb, Wih1, bih1, bhh1,
                                           Wih2, bih2, bhh2, tab1, tab2);
    lstm_main<<<Bsz / RPB, 256, 0, stream>>>(s1, s2, l1, l2, tab1, tab2,
                                             Whh1, Whh2, Wl1, bl1, Wl2, bl2, out);
}

// Round 2
// 491.831 us; speedup vs baseline: 1.3796x; 1.3796x over previous
//
#include <hip/hip_runtime.h>

#define Bsz 1024
#define Tt  256
#define Vv  32004
#define Dd  50
#define Hh  64
#define RR  32   // vocab rows per build_tables block
#define RPB 8    // batch rows per lstm_main block

typedef __bf16 b16x8 __attribute__((ext_vector_type(8)));
typedef float  f32x4 __attribute__((ext_vector_type(4)));

// barrier WITHOUT vmcnt(0) drain: LDS ordering only, in-flight global loads
// (the xw register prefetch) survive across it.
__device__ __forceinline__ void barrier_novm() {
    asm volatile("s_waitcnt lgkmcnt(0)\n\ts_barrier" ::: "memory");
}
__device__ __forceinline__ float fsig(float x) {
    return __fdividef(1.0f, 1.0f + __expf(-x));
}
__device__ __forceinline__ float ftanh(float x) {
    return 2.0f * __fdividef(1.0f, 1.0f + __expf(-2.0f * x)) - 1.0f;
}

// ---------------------------------------------------------------------------
// Prologue: tab[v][g] = sum_d emb[v][d] * Wih[g][d] + bih[g] + bhh[g]
// (register-resident W; proved perf-neutral vs LDS variant, kept for low LDS)
// ---------------------------------------------------------------------------
__launch_bounds__(256)
__global__ void build_tables(const float* __restrict__ emb,
                             const float* __restrict__ Wih1,
                             const float* __restrict__ bih1,
                             const float* __restrict__ bhh1,
                             const float* __restrict__ Wih2,
                             const float* __restrict__ bih2,
                             const float* __restrict__ bhh2,
                             float* __restrict__ tab1,
                             float* __restrict__ tab2) {
    const int v0 = blockIdx.x * RR;
    const int g  = threadIdx.x;
    const int nr = min(RR, Vv - v0);

    const float* Wih = blockIdx.y ? Wih2 : Wih1;
    const float* bih = blockIdx.y ? bih2 : bih1;
    const float* bhh = blockIdx.y ? bhh2 : bhh1;
    float*       tab = blockIdx.y ? tab2 : tab1;

    __shared__ __align__(16) float elds[RR * 52];

    float4 wreg[13];
    {
        const float* wrow = Wih + (size_t)g * Dd;
#pragma unroll
        for (int j = 0; j < 12; ++j) {
            const float2 a = *(const float2*)(wrow + 4 * j);
            const float2 b = *(const float2*)(wrow + 4 * j + 2);
            wreg[j] = make_float4(a.x, a.y, b.x, b.y);
        }
        const float2 t = *(const float2*)(wrow + 48);
        wreg[12] = make_float4(t.x, t.y, 0.0f, 0.0f);
    }
    for (int i = threadIdx.x; i < nr * 52; i += 256) {
        const int row = i / 52;
        const int col = i - row * 52;
        elds[i] = (col < Dd) ? emb[(size_t)(v0 + row) * Dd + col] : 0.0f;
    }
    __syncthreads();

    const float bias = bih[g] + bhh[g];

    for (int c = 0; c < RR / 8; ++c) {
        const int r0 = c * 8;
        float acc[8];
#pragma unroll
        for (int r = 0; r < 8; ++r) acc[r] = 0.0f;
#pragma unroll
        for (int j = 0; j < 13; ++j) {
            const float4 w = wreg[j];
#pragma unroll
            for (int r = 0; r < 8; ++r) {
                const float4 e = *(const float4*)(&elds[(r0 + r) * 52 + 4 * j]);
                acc[r] += e.x * w.x + e.y * w.y + e.z * w.z + e.w * w.w;
            }
        }
#pragma unroll
        for (int r = 0; r < 8; ++r) {
            const int row = r0 + r;
            if (row < nr)
                tab[(size_t)(v0 + row) * 256 + g] = acc[r] + bias;
        }
    }
}

// ---------------------------------------------------------------------------
// v3 recurrence: 128 blocks x 8 batch rows, 512 threads (8 waves).
// Waves = (ut, WH): ut = unit-tile [16ut,16ut+16), WH = compile-time r-pair
// bit. Waves (ut,0) and (ut,1) run IDENTICAL MFMAs (redundancy is free at
// 1.4% MfmaUtil); B columns 8-15 broadcast-duplicate rows 0-7 (hsh[mn&7]).
// Lane (q,mn): row = mn&7, r = 2*WH + (mn>>3)  ->  EXACTLY 1 unit-update per
// lane (v2 had 4 -> 320 cyc of serial transcendentals on the critical path).
// Gates stay in registers (compile-time acc indices); xw = 4 scalar loads of
// the lane's own unit (redundant waves cover disjoint units -> no extra
// traffic), prefetch distance 4. One novm-barrier per step. toklds
// transposed to [t][row]: uniform-t read = conflict-free (was 16-way).
// ---------------------------------------------------------------------------
template <int WH>
__device__ __forceinline__ void lstm_phases(
    const int* __restrict__ s1, const int* __restrict__ s2,
    const int* __restrict__ len1, const int* __restrict__ len2,
    const float* __restrict__ tab1, const float* __restrict__ tab2,
    const float* __restrict__ Whh1, const float* __restrict__ Whh2,
    int b0, int tid,
    __bf16 (*hsh)[RPB][72],   // [2][RPB][72]
    int (*toklds)[RPB],       // [Tt][RPB]
    float (*h2s)[Hh])         // [RPB][Hh]
{
    const int w    = tid >> 6;
    const int lane = tid & 63;
    const int q    = lane >> 4;       // MFMA quad
    const int mn   = lane & 15;       // B/C column
    const int ut   = w >> 1;          // unit tile
    const int row  = mn & 7;          // batch row within block
    const int lh   = mn >> 3;         // lane-half bit -> r LSB
    const int u_own = 16 * ut + 4 * q + 2 * WH + lh;  // this lane's hidden unit

    float c = 0.0f, selh = 0.0f, selc = 0.0f;
    const f32x4 zero4 = {0.0f, 0.0f, 0.0f, 0.0f};

    for (int phase = 0; phase < 2; ++phase) {
        const float* tab  = phase ? tab2 : tab1;
        const float* Whh  = phase ? Whh2 : Whh1;
        const int*   sent = phase ? s2 : s1;
        const int*   lenp = phase ? len2 : len1;

        // stage tokens transposed: toklds[t][row] (coalesced global reads)
        for (int i = tid; i < RPB * Tt; i += 512) {
            const int r = i >> 8, t = i & 255;
            toklds[t][r] = sent[(size_t)(b0 + r) * Tt + t];
        }

        // A fragments: A[m = mn][k = 8q + j] = Whh[64k + 16ut + mn][...]
        b16x8 af[8];
#pragma unroll
        for (int k = 0; k < 4; ++k) {
            const int gate = 64 * k + 16 * ut + mn;
#pragma unroll
            for (int kh = 0; kh < 2; ++kh) {
                const float* ar = Whh + (size_t)gate * Hh + kh * 32 + q * 8;
                const float4 f0 = *(const float4*)ar;
                const float4 f1 = *(const float4*)(ar + 4);
                b16x8 a;
                a[0] = (__bf16)f0.x; a[1] = (__bf16)f0.y;
                a[2] = (__bf16)f0.z; a[3] = (__bf16)f0.w;
                a[4] = (__bf16)f1.x; a[5] = (__bf16)f1.y;
                a[6] = (__bf16)f1.z; a[7] = (__bf16)f1.w;
                af[2 * k + kh] = a;
            }
        }

        const int mi = lenp[(size_t)(b0 + row) * Hh + u_own];

        // seed h/c (zeros phase 0, gathered state phase 1)
        const float h0 = phase ? selh : 0.0f;
        c = phase ? selc : 0.0f;
        hsh[0][row][u_own] = (__bf16)h0;
        selh = 0.0f; selc = 0.0f;
        __syncthreads();

        // xw scalar prefetch, distance 4: S = tab[token][64k + u_own], k=0..3
        const float* tabu = tab + u_own;
        float4 Sa, Sb, Sc, Sd;
        auto prime = [&](int t, float4& S) {
            const float* tp = tabu + (size_t)toklds[t][row] * 256;
            S.x = tp[0]; S.y = tp[64]; S.z = tp[128]; S.w = tp[192];
        };
        prime(0, Sa); prime(1, Sb); prime(2, Sc); prime(3, Sd);

        auto step = [&](int t, float4& S, int rb, int wb) {
            // B frags: broadcast-duplicated across column halves (mn&7)
            const b16x8 bf0 = *(const b16x8*)&hsh[rb][row][q * 8];
            const b16x8 bf1 = *(const b16x8*)&hsh[rb][row][32 + q * 8];
            const int tn = (t + 4 < Tt) ? t + 4 : Tt - 1;
            const int tk = toklds[tn][row];

            f32x4 acc[4];
#pragma unroll
            for (int k = 0; k < 4; ++k) {
                acc[k] = __builtin_amdgcn_mfma_f32_16x16x32_bf16(af[2 * k],     bf0, zero4,  0, 0, 0);
                acc[k] = __builtin_amdgcn_mfma_f32_16x16x32_bf16(af[2 * k + 1], bf1, acc[k], 0, 0, 0);
            }
            // gate extraction: compile-time indices, one cndmask per gate
            const float gI = (lh ? acc[0][2 * WH + 1] : acc[0][2 * WH]) + S.x;
            const float gF = (lh ? acc[1][2 * WH + 1] : acc[1][2 * WH]) + S.y;
            const float gG = (lh ? acc[2][2 * WH + 1] : acc[2][2 * WH]) + S.z;
            const float gO = (lh ? acc[3][2 * WH + 1] : acc[3][2 * WH]) + S.w;
            // refill S for t+4 (WAR on S after the adds above)
            const float* tp = tabu + (size_t)tk * 256;
            S.x = tp[0]; S.y = tp[64]; S.z = tp[128]; S.w = tp[192];

            const float iv = fsig(gI);
            const float fv = fsig(gF);
            const float gv = ftanh(gG);
            const float ov = fsig(gO);
            c = fv * c + iv * gv;
            const float hv = ov * ftanh(c);
            hsh[wb][row][u_own] = (__bf16)hv;
            if (t == mi) { selh = hv; selc = c; }
            barrier_novm();   // ONE barrier/step; global prefetch stays in flight
        };

        for (int t = 0; t < Tt; t += 4) {
            step(t,     Sa, 0, 1);
            step(t + 1, Sb, 1, 0);
            step(t + 2, Sc, 0, 1);
            step(t + 3, Sd, 1, 0);
        }
    }

    h2s[row][u_own] = selh;
}

__launch_bounds__(512, 2)
__global__ void lstm_main(const int*   __restrict__ s1,
                          const int*   __restrict__ s2,
                          const int*   __restrict__ len1,
                          const int*   __restrict__ len2,
                          const float* __restrict__ tab1,
                          const float* __restrict__ tab2,
                          const float* __restrict__ Whh1,
                          const float* __restrict__ Whh2,
                          const float* __restrict__ Wl1,
                          const float* __restrict__ bl1,
                          const float* __restrict__ Wl2,
                          const float* __restrict__ bl2,
                          float* __restrict__ out) {
    const int tid = threadIdx.x;
    const int b0  = blockIdx.x * RPB;

    __shared__ __align__(16) __bf16 hsh[2][RPB][72];
    __shared__ int   toklds[Tt][RPB];
    __shared__ float h2s[RPB][Hh];
    __shared__ float ys[RPB][128];

    // scalar branch (readfirstlane -> SGPR): each wave runs exactly one
    // instantiation; barrier sequences in both are identical (wave-counted
    // s_barrier pairs across program counters).
    if (__builtin_amdgcn_readfirstlane((tid >> 6) & 1) == 0)
        lstm_phases<0>(s1, s2, len1, len2, tab1, tab2, Whh1, Whh2,
                       b0, tid, hsh, toklds, h2s);
    else
        lstm_phases<1>(s1, s2, len1, len2, tab1, tab2, Whh1, Whh2,
                       b0, tid, hsh, toklds, h2s);
    __syncthreads();

    // ---------------- epilogue MLP on the 8 gathered rows -------------------
#pragma unroll
    for (int p = 0; p < 2; ++p) {
        const int idx = tid + 512 * p;        // 1024 (row, neuron) tasks
        const int rr = idx >> 7, n = idx & 127;
        float a = bl1[n];
        const float* wl = Wl1 + n * 64;
#pragma unroll 8
        for (int k = 0; k < 64; ++k) a += h2s[rr][k] * wl[k];
        ys[rr][n] = ftanh(a);
    }
    __syncthreads();
    if (tid < 32) {
        const int rr = tid >> 2, o = tid & 3;
        float a = bl2[o];
        const float* wl = Wl2 + o * 128;
#pragma unroll 8
        for (int k = 0; k < 128; ++k) a += ys[rr][k] * wl[k];
        out[(size_t)(b0 + rr) * 4 + o] = a;
    }
}

// ---------------------------------------------------------------------------
extern "C" void kernel_launch(void* const* d_in, const int* in_sizes, int n_in,
                              void* d_out, int out_size, void* d_ws, size_t ws_size,
                              hipStream_t stream) {
    const int*   s1   = (const int*)d_in[0];
    const int*   s2   = (const int*)d_in[1];
    const int*   l1   = (const int*)d_in[2];
    const int*   l2   = (const int*)d_in[3];
    // d_in[4], d_in[5] (s1_s, s2_s) unused by the reference
    const float* emb  = (const float*)d_in[6];
    const float* Wih1 = (const float*)d_in[7];
    const float* Whh1 = (const float*)d_in[8];
    const float* bih1 = (const float*)d_in[9];
    const float* bhh1 = (const float*)d_in[10];
    const float* Wih2 = (const float*)d_in[11];
    const float* Whh2 = (const float*)d_in[12];
    const float* bih2 = (const float*)d_in[13];
    const float* bhh2 = (const float*)d_in[14];
    const float* Wl1  = (const float*)d_in[15];
    const float* bl1  = (const float*)d_in[16];
    const float* Wl2  = (const float*)d_in[17];
    const float* bl2  = (const float*)d_in[18];
    float* out = (float*)d_out;

    float* tab1 = (float*)d_ws;                       // [V,256] fp32
    float* tab2 = tab1 + (size_t)Vv * 256;            // [V,256] fp32  (65.6 MB)

    dim3 grid((Vv + RR - 1) / RR, 2);
    build_tables<<<grid, 256, 0, stream>>>(emb, Wih1, bih1, bhh1,
                                           Wih2, bih2, bhh2, tab1, tab2);
    lstm_main<<<Bsz / RPB, 512, 0, stream>>>(s1, s2, l1, l2, tab1, tab2,
                                             Whh1, Whh2, Wl1, bl1, Wl2, bl2, out);
}

// Round 3
// 334.558 us; speedup vs baseline: 2.0281x; 1.4701x over previous
//
#include <hip/hip_runtime.h>

#define Bsz 1024
#define Tt  256
#define Vv  32004
#define Dd  50
#define Hh  64
#define MB  64   // vocab rows per build_tables block

typedef __bf16 b16x8 __attribute__((ext_vector_type(8)));
typedef float  f32x4 __attribute__((ext_vector_type(4)));

// barrier WITHOUT vmcnt(0) drain: LDS ordering only, in-flight global loads
// (the xw register prefetch) survive across it.
__device__ __forceinline__ void barrier_novm() {
    asm volatile("s_waitcnt lgkmcnt(0)\n\ts_barrier" ::: "memory");
}
__device__ __forceinline__ float fsig(float x) {
    return __fdividef(1.0f, 1.0f + __expf(-x));
}
__device__ __forceinline__ float ftanh(float x) {
    return 2.0f * __fdividef(1.0f, 1.0f + __expf(-2.0f * x)) - 1.0f;
}

// fp32 -> bf16 hi/lo split (3-term product keeps ~fp32 accuracy: rel err ~2^-16)
__device__ __forceinline__ void cvt_hilo(const float* x, b16x8& hi, b16x8& lo) {
#pragma unroll
    for (int e = 0; e < 8; ++e) {
        const __bf16 h = (__bf16)x[e];
        hi[e] = h;
        lo[e] = (__bf16)(x[e] - (float)h);
    }
}

// ---------------------------------------------------------------------------
// Prologue v3: MFMA GEMM  tab[v][unit*4+gate] = emb[v,:] . Wih[g,:] + bias[g].
// Old version: 416 uniform ds_read_b128 + 1664 scalar FMA per thread (~150us).
// Now: A = emb rows (bf16 hi/lo), B = Wih^T frags in registers, 3-term MFMA
// (hi*hi + hi*lo + lo*hi), zero LDS. K padded 50->64 with zeros.
// Store layout is UNIT-MAJOR: pos = (g&63)*4 + (g>>6), so lstm_main reads one
// float4 per (token, unit) = all 4 gate xw values.
// ---------------------------------------------------------------------------
__launch_bounds__(256)
__global__ void build_tables(const float* __restrict__ emb,
                             const float* __restrict__ Wih1,
                             const float* __restrict__ bih1,
                             const float* __restrict__ bhh1,
                             const float* __restrict__ Wih2,
                             const float* __restrict__ bih2,
                             const float* __restrict__ bhh2,
                             float* __restrict__ tab1,
                             float* __restrict__ tab2) {
    const int tid  = threadIdx.x;
    const int w    = tid >> 6;        // wave: gate-type block (64 gates)
    const int lane = tid & 63;
    const int q    = lane >> 4;
    const int mn   = lane & 15;
    const int v0   = blockIdx.x * MB;

    const float* Wih = blockIdx.y ? Wih2 : Wih1;
    const float* bih = blockIdx.y ? bih2 : bih1;
    const float* bhh = blockIdx.y ? bhh2 : bhh1;
    float*       tab = blockIdx.y ? tab2 : tab1;

    // B fragments (Wih^T): 4 n-tiles x 2 k-halves, hi/lo.  B[k=8q+j][n=mn].
    b16x8 bh[4][2], bl[4][2];
    float biasv[4];
#pragma unroll
    for (int tn = 0; tn < 4; ++tn) {
        const int g = 64 * w + 16 * tn + mn;
        const float* wr = Wih + (size_t)g * Dd;
        float x[8];
        // k-half 0: cols 8q..8q+7 (all < 32 < Dd); rows are 8B-aligned
#pragma unroll
        for (int j = 0; j < 8; j += 2) {
            const float2 t2 = *(const float2*)(wr + 8 * q + j);
            x[j] = t2.x; x[j + 1] = t2.y;
        }
        cvt_hilo(x, bh[tn][0], bl[tn][0]);
        // k-half 1: cols 32+8q+j, zero-padded past Dd (also avoids reading
        // the next row's data through a wide load)
#pragma unroll
        for (int j = 0; j < 8; ++j) {
            const int col = 32 + 8 * q + j;
            x[j] = (col < Dd) ? wr[col] : 0.0f;
        }
        cvt_hilo(x, bh[tn][1], bl[tn][1]);
        biasv[tn] = bih[g] + bhh[g];
    }

#pragma unroll
    for (int m = 0; m < 4; ++m) {
        // A fragment: A[mrow=mn][k] = emb[v0+16m+mn][k]; clamp OOB rows (their
        // stores are masked below)
        const int v = v0 + 16 * m + mn;
        const float* er = emb + (size_t)(v < Vv ? v : Vv - 1) * Dd;
        b16x8 ah[2], al[2];
        float x[8];
#pragma unroll
        for (int j = 0; j < 8; j += 2) {
            const float2 t2 = *(const float2*)(er + 8 * q + j);
            x[j] = t2.x; x[j + 1] = t2.y;
        }
        cvt_hilo(x, ah[0], al[0]);
#pragma unroll
        for (int j = 0; j < 8; ++j) {
            const int col = 32 + 8 * q + j;
            x[j] = (col < Dd) ? er[col] : 0.0f;
        }
        cvt_hilo(x, ah[1], al[1]);

#pragma unroll
        for (int tn = 0; tn < 4; ++tn) {
            f32x4 a = {0.0f, 0.0f, 0.0f, 0.0f};
#pragma unroll
            for (int kh = 0; kh < 2; ++kh) {
                a = __builtin_amdgcn_mfma_f32_16x16x32_bf16(ah[kh], bh[tn][kh], a, 0, 0, 0);
                a = __builtin_amdgcn_mfma_f32_16x16x32_bf16(ah[kh], bl[tn][kh], a, 0, 0, 0);
                a = __builtin_amdgcn_mfma_f32_16x16x32_bf16(al[kh], bh[tn][kh], a, 0, 0, 0);
            }
            // C[mrow=4q+r][n=mn] -> vocab row v0+16m+4q+r, gate 64w+16tn+mn,
            // stored unit-major: tab[v][ (16tn+mn)*4 + w ]
#pragma unroll
            for (int r = 0; r < 4; ++r) {
                const int vr = v0 + 16 * m + 4 * q + r;
                if (vr < Vv)
                    tab[(size_t)vr * 256 + (16 * tn + mn) * 4 + w] = a[r] + biasv[tn];
            }
        }
    }
}

// ---------------------------------------------------------------------------
// v4 recurrence: 256 blocks x 4 batch rows, 256 threads (4 waves, 1/SIMD —
// v3's redundant-wave pairs doubled per-SIMD issue to 60% busy for zero chain
// shortening; reverted). Wave w owns units [16w,16w+16) for ALL gate types.
// B columns duplicate 4x (hsh[mn&3], LDS broadcast = free); the duplicated
// C column-groups give each lane a free selector rsel=mn>>2: lane (q,mn)
// updates exactly unit 16w+4q+rsel of row mn&3 via 3 cndmasks (static element
// indices). Gates never leave registers; ONE novm-barrier per step with
// double-buffered hsh. xw = ONE coalesced dwordx4 per step (unit-major tab),
// prefetch distance 4. hsh row stride 192B (48 dwords == 16 mod 32): the 16
// distinct ds_read_b128 tile all 32 banks exactly 2-way = conflict-free.
// ---------------------------------------------------------------------------
__launch_bounds__(256, 1)
__global__ void lstm_main(const int*   __restrict__ s1,
                          const int*   __restrict__ s2,
                          const int*   __restrict__ len1,
                          const int*   __restrict__ len2,
                          const float* __restrict__ tab1,
                          const float* __restrict__ tab2,
                          const float* __restrict__ Whh1,
                          const float* __restrict__ Whh2,
                          const float* __restrict__ Wl1,
                          const float* __restrict__ bl1,
                          const float* __restrict__ Wl2,
                          const float* __restrict__ bl2,
                          float* __restrict__ out) {
    const int tid  = threadIdx.x;
    const int w    = tid >> 6;        // wave: unit tile [16w,16w+16)
    const int lane = tid & 63;
    const int q    = lane >> 4;       // MFMA quad
    const int mn   = lane & 15;       // B/C column
    const int row  = mn & 3;          // batch row within block
    const bool sb0 = (mn >> 2) & 1;   // rsel bit0
    const bool sb1 = (mn >> 3) & 1;   // rsel bit1
    const int u_own = 16 * w + 4 * q + (mn >> 2);  // this lane's hidden unit
    const int b0   = blockIdx.x * 4;

    __shared__ __align__(16) __bf16 hsh[2][4][96];  // stride 96 units = 192B
    __shared__ int   toklds[Tt][4];                 // transposed: uniform-t read
    __shared__ float h2s[4][64];
    __shared__ float ys[4][128];

    float c = 0.0f, selh = 0.0f, selc = 0.0f;
    const f32x4 zero4 = {0.0f, 0.0f, 0.0f, 0.0f};

    for (int phase = 0; phase < 2; ++phase) {
        const float* tab  = phase ? tab2 : tab1;
        const float* Whh  = phase ? Whh2 : Whh1;
        const int*   sent = phase ? s2 : s1;
        const int*   lenp = phase ? len2 : len1;

        // stage tokens transposed (coalesced reads; one-time 4 iterations)
        for (int i = tid; i < 4 * Tt; i += 256)
            toklds[i & 255][i >> 8] = sent[(size_t)(b0 + (i >> 8)) * Tt + (i & 255)];

        // A fragments: m-tile k (gate-type) covers gates 64k+16w+0..15.
        // A[m=mn][kdim=8q+j] = Whh[64k+16w+mn][kh*32+8q+j]
        b16x8 af[8];
#pragma unroll
        for (int k = 0; k < 4; ++k) {
            const int gate = 64 * k + 16 * w + mn;
#pragma unroll
            for (int kh = 0; kh < 2; ++kh) {
                const float* ar = Whh + (size_t)gate * Hh + kh * 32 + q * 8;
                const float4 f0 = *(const float4*)ar;
                const float4 f1 = *(const float4*)(ar + 4);
                b16x8 a;
                a[0] = (__bf16)f0.x; a[1] = (__bf16)f0.y;
                a[2] = (__bf16)f0.z; a[3] = (__bf16)f0.w;
                a[4] = (__bf16)f1.x; a[5] = (__bf16)f1.y;
                a[6] = (__bf16)f1.z; a[7] = (__bf16)f1.w;
                af[2 * k + kh] = a;
            }
        }

        const int mi = lenp[(size_t)(b0 + row) * Hh + u_own];

        // seed h/c (zeros phase 0, gathered state phase 1) into buffer 0
        const float h0f = phase ? selh : 0.0f;
        c = phase ? selc : 0.0f;
        hsh[0][row][u_own] = (__bf16)h0f;
        selh = 0.0f; selc = 0.0f;
        __syncthreads();

        // xw prefetch, distance 4: one float4 = all 4 gate xw of (token, u_own)
        const float* tu = tab + 4 * u_own;
        f32x4 Sa, Sb, Sc, Sd;
        auto prime = [&](int t, f32x4& S) {
            S = *(const f32x4*)(tu + (size_t)toklds[t][row] * 256);
        };
        prime(0, Sa); prime(1, Sb); prime(2, Sc); prime(3, Sd);

        // select acc element rsel (2-bit, runtime) with static element indices
        auto pick = [&](const f32x4& a) -> float {
            const float e01 = sb0 ? a[1] : a[0];
            const float e23 = sb0 ? a[3] : a[2];
            return sb1 ? e23 : e01;
        };

        auto step = [&](int t, f32x4& S, int rb, int wb) {
            // B frags: 4x column-duplicated rows (broadcast read = free)
            const b16x8 bf0 = *(const b16x8*)&hsh[rb][row][q * 8];
            const b16x8 bf1 = *(const b16x8*)&hsh[rb][row][32 + q * 8];
            const int tnext = (t + 4 < Tt) ? t + 4 : Tt - 1;
            const int tk = toklds[tnext][row];

            f32x4 a0 = __builtin_amdgcn_mfma_f32_16x16x32_bf16(af[0], bf0, zero4, 0, 0, 0);
            a0 = __builtin_amdgcn_mfma_f32_16x16x32_bf16(af[1], bf1, a0, 0, 0, 0);
            f32x4 a1 = __builtin_amdgcn_mfma_f32_16x16x32_bf16(af[2], bf0, zero4, 0, 0, 0);
            a1 = __builtin_amdgcn_mfma_f32_16x16x32_bf16(af[3], bf1, a1, 0, 0, 0);
            f32x4 a2 = __builtin_amdgcn_mfma_f32_16x16x32_bf16(af[4], bf0, zero4, 0, 0, 0);
            a2 = __builtin_amdgcn_mfma_f32_16x16x32_bf16(af[5], bf1, a2, 0, 0, 0);
            f32x4 a3 = __builtin_amdgcn_mfma_f32_16x16x32_bf16(af[6], bf0, zero4, 0, 0, 0);
            a3 = __builtin_amdgcn_mfma_f32_16x16x32_bf16(af[7], bf1, a3, 0, 0, 0);

            const float gI = pick(a0) + S[0];
            const float gF = pick(a1) + S[1];
            const float gG = pick(a2) + S[2];
            const float gO = pick(a3) + S[3];
            // refill S for t+4 (WAR on S keeps issue after the adds above)
            S = *(const f32x4*)(tu + (size_t)tk * 256);

            const float iv = fsig(gI);
            const float fv = fsig(gF);
            const float gv = ftanh(gG);
            const float ov = fsig(gO);
            c = fv * c + iv * gv;
            const float hv = ov * ftanh(c);
            hsh[wb][row][u_own] = (__bf16)hv;
            if (t == mi) { selh = hv; selc = c; }
            barrier_novm();   // ONE barrier/step; global prefetch stays in flight
        };

        for (int t = 0; t < Tt; t += 4) {
            step(t,     Sa, 0, 1);
            step(t + 1, Sb, 1, 0);
            step(t + 2, Sc, 0, 1);
            step(t + 3, Sd, 1, 0);
        }
    }

    // ---------------- epilogue MLP on the 4 gathered rows -------------------
    h2s[row][u_own] = selh;
    __syncthreads();
#pragma unroll
    for (int p = 0; p < 2; ++p) {
        const int idx = tid + 256 * p;        // 512 (row, neuron) tasks
        const int rr = idx >> 7, n = idx & 127;
        float a = bl1[n];
        const float* wl = Wl1 + n * 64;
#pragma unroll 8
        for (int k = 0; k < 64; ++k) a += h2s[rr][k] * wl[k];
        ys[rr][n] = ftanh(a);
    }
    __syncthreads();
    if (tid < 16) {
        const int rr = tid >> 2, o = tid & 3;
        float a = bl2[o];
        const float* wl = Wl2 + o * 128;
#pragma unroll 8
        for (int k = 0; k < 128; ++k) a += ys[rr][k] * wl[k];
        out[(size_t)(b0 + rr) * 4 + o] = a;
    }
}

// ---------------------------------------------------------------------------
extern "C" void kernel_launch(void* const* d_in, const int* in_sizes, int n_in,
                              void* d_out, int out_size, void* d_ws, size_t ws_size,
                              hipStream_t stream) {
    const int*   s1   = (const int*)d_in[0];
    const int*   s2   = (const int*)d_in[1];
    const int*   l1   = (const int*)d_in[2];
    const int*   l2   = (const int*)d_in[3];
    // d_in[4], d_in[5] (s1_s, s2_s) unused by the reference
    const float* emb  = (const float*)d_in[6];
    const float* Wih1 = (const float*)d_in[7];
    const float* Whh1 = (const float*)d_in[8];
    const float* bih1 = (const float*)d_in[9];
    const float* bhh1 = (const float*)d_in[10];
    const float* Wih2 = (const float*)d_in[11];
    const float* Whh2 = (const float*)d_in[12];
    const float* bih2 = (const float*)d_in[13];
    const float* bhh2 = (const float*)d_in[14];
    const float* Wl1  = (const float*)d_in[15];
    const float* bl1  = (const float*)d_in[16];
    const float* Wl2  = (const float*)d_in[17];
    const float* bl2  = (const float*)d_in[18];
    float* out = (float*)d_out;

    float* tab1 = (float*)d_ws;                       // [V,256] fp32, unit-major
    float* tab2 = tab1 + (size_t)Vv * 256;            // [V,256] fp32  (65.6 MB)

    dim3 grid((Vv + MB - 1) / MB, 2);
    build_tables<<<grid, 256, 0, stream>>>(emb, Wih1, bih1, bhh1,
                                           Wih2, bih2, bhh2, tab1, tab2);
    lstm_main<<<Bsz / 4, 256, 0, stream>>>(s1, s2, l1, l2, tab1, tab2,
                                           Whh1, Whh2, Wl1, bl1, Wl2, bl2, out);
}

// Round 5
// 283.320 us; speedup vs baseline: 2.3948x; 1.1809x over previous
//
#include <hip/hip_runtime.h>

#define Bsz 1024
#define Tt  256
#define Vv  32004
#define Dd  50
#define Hh  64
#define MB  64   // vocab rows per build_tables block

typedef __bf16 b16x8 __attribute__((ext_vector_type(8)));
typedef float  f32x4 __attribute__((ext_vector_type(4)));

// barrier WITHOUT vmcnt(0) drain: LDS ordering only, in-flight global loads
// (the xw register prefetch) survive across it.
__device__ __forceinline__ void barrier_novm() {
    asm volatile("s_waitcnt lgkmcnt(0)\n\ts_barrier" ::: "memory");
}
// Fast activations via raw gfx950 opcodes (inline asm avoids any builtin-
// availability question): v_exp_f32 = 2^x, v_rcp_f32 = 1/x, both 1-ulp.
// Plain fp32 division w/o -ffast-math lowers to the IEEE div_scale/div_fmas/
// div_fixup sequence (~10 dependent VALU each); 5 per LSTM step ~= 300 cyc of
// the 1100-cyc step (VALUBusy 51%). These are 2 trans + 3 VALU each.
__device__ __forceinline__ float fexp2(float x) {
    float r;
    asm("v_exp_f32 %0, %1" : "=v"(r) : "v"(x));
    return r;
}
__device__ __forceinline__ float frcp(float x) {
    float r;
    asm("v_rcp_f32 %0, %1" : "=v"(r) : "v"(x));
    return r;
}
__device__ __forceinline__ float fsig(float x) {
    return frcp(1.0f + fexp2(x * -1.442695041f));                // 1/(1+e^-x)
}
__device__ __forceinline__ float ftanh(float x) {
    return 2.0f * frcp(1.0f + fexp2(x * -2.885390082f)) - 1.0f;  // 2/(1+e^-2x)-1
}

// fp32 -> bf16 hi/lo split (3-term product keeps ~fp32 accuracy)
__device__ __forceinline__ void cvt_hilo(const float* x, b16x8& hi, b16x8& lo) {
#pragma unroll
    for (int e = 0; e < 8; ++e) {
        const __bf16 h = (__bf16)x[e];
        hi[e] = h;
        lo[e] = (__bf16)(x[e] - (float)h);
    }
}

// ---------------------------------------------------------------------------
// Prologue v4: MFMA GEMM  tab[v][unit*4+gate] = emb[v,:] . Wih[g,:] + bias.
// v3's store scattered each lane's dword at 64B stride (64 cache lines per
// wave-store, ~16x write amplification -> ~98us). Now wave w owns UNITS
// 16w..16w+15 for all 4 gate types (k-tile = gate type, same mapping as
// lstm_main's A-frags): lane (q,mn) holds i,f,g,o of unit 16w+mn in
// acc[0..3][r] and stores ONE contiguous dwordx4 per vocab row. 16 lanes =
// contiguous 256B segment -> fully coalesced.
// ---------------------------------------------------------------------------
__launch_bounds__(256)
__global__ void build_tables(const float* __restrict__ emb,
                             const float* __restrict__ Wih1,
                             const float* __restrict__ bih1,
                             const float* __restrict__ bhh1,
                             const float* __restrict__ Wih2,
                             const float* __restrict__ bih2,
                             const float* __restrict__ bhh2,
                             float* __restrict__ tab1,
                             float* __restrict__ tab2) {
    const int tid  = threadIdx.x;
    const int w    = tid >> 6;        // wave: unit tile 16w..16w+15
    const int lane = tid & 63;
    const int q    = lane >> 4;
    const int mn   = lane & 15;
    const int v0   = blockIdx.x * MB;

    const float* Wih = blockIdx.y ? Wih2 : Wih1;
    const float* bih = blockIdx.y ? bih2 : bih1;
    const float* bhh = blockIdx.y ? bhh2 : bhh1;
    float*       tab = blockIdx.y ? tab2 : tab1;

    // B fragments (Wih^T), gate-type k: B[kd=8q+j][n=mn] = Wih[64k+16w+mn][...]
    b16x8 bh[4][2], bl[4][2];
    f32x4 bias4;
#pragma unroll
    for (int k = 0; k < 4; ++k) {
        const int g = 64 * k + 16 * w + mn;
        const float* wr = Wih + (size_t)g * Dd;
        float x[8];
#pragma unroll
        for (int j = 0; j < 8; j += 2) {           // k-half 0: cols 8q..8q+7 < 32
            const float2 t2 = *(const float2*)(wr + 8 * q + j);
            x[j] = t2.x; x[j + 1] = t2.y;
        }
        cvt_hilo(x, bh[k][0], bl[k][0]);
#pragma unroll
        for (int j = 0; j < 8; ++j) {              // k-half 1: cols 32+8q+j, pad
            const int col = 32 + 8 * q + j;
            x[j] = (col < Dd) ? wr[col] : 0.0f;
        }
        cvt_hilo(x, bh[k][1], bl[k][1]);
        bias4[k] = bih[g] + bhh[g];
    }

#pragma unroll
    for (int m = 0; m < 4; ++m) {
        // A fragment: A[mr=mn][kd] = emb[v0+16m+mn][kd]; clamp OOB rows
        const int v = v0 + 16 * m + mn;
        const float* er = emb + (size_t)(v < Vv ? v : Vv - 1) * Dd;
        b16x8 ah[2], al[2];
        float x[8];
#pragma unroll
        for (int j = 0; j < 8; j += 2) {
            const float2 t2 = *(const float2*)(er + 8 * q + j);
            x[j] = t2.x; x[j + 1] = t2.y;
        }
        cvt_hilo(x, ah[0], al[0]);
#pragma unroll
        for (int j = 0; j < 8; ++j) {
            const int col = 32 + 8 * q + j;
            x[j] = (col < Dd) ? er[col] : 0.0f;
        }
        cvt_hilo(x, ah[1], al[1]);

        f32x4 acc[4];
#pragma unroll
        for (int k = 0; k < 4; ++k) {
            f32x4 a = {0.0f, 0.0f, 0.0f, 0.0f};
#pragma unroll
            for (int kh = 0; kh < 2; ++kh) {
                a = __builtin_amdgcn_mfma_f32_16x16x32_bf16(ah[kh], bh[k][kh], a, 0, 0, 0);
                a = __builtin_amdgcn_mfma_f32_16x16x32_bf16(ah[kh], bl[k][kh], a, 0, 0, 0);
                a = __builtin_amdgcn_mfma_f32_16x16x32_bf16(al[kh], bh[k][kh], a, 0, 0, 0);
            }
            acc[k] = a;
        }
        // store: one contiguous float4 {i,f,g,o}+bias per (lane, r)
#pragma unroll
        for (int r = 0; r < 4; ++r) {
            const int vr = v0 + 16 * m + 4 * q + r;
            if (vr < Vv) {
                f32x4 o;
                o[0] = acc[0][r] + bias4[0];
                o[1] = acc[1][r] + bias4[1];
                o[2] = acc[2][r] + bias4[2];
                o[3] = acc[3][r] + bias4[3];
                *(f32x4*)(tab + (size_t)vr * 256 + (16 * w + mn) * 4) = o;
            }
        }
    }
}

// ---------------------------------------------------------------------------
// v5 recurrence: identical structure to v4 (256 blocks x 4 rows, 4 waves,
// in-register gates, 1 novm-barrier/step, unit-major tab -> one dwordx4
// xw load/step, distance-4 prefetch). Changes: fast rcp/exp activations
// (see fsig/ftanh) and MFMA order g,i,f,o so the tanh(g) chain starts first.
// ---------------------------------------------------------------------------
__launch_bounds__(256, 1)
__global__ void lstm_main(const int*   __restrict__ s1,
                          const int*   __restrict__ s2,
                          const int*   __restrict__ len1,
                          const int*   __restrict__ len2,
                          const float* __restrict__ tab1,
                          const float* __restrict__ tab2,
                          const float* __restrict__ Whh1,
                          const float* __restrict__ Whh2,
                          const float* __restrict__ Wl1,
                          const float* __restrict__ bl1,
                          const float* __restrict__ Wl2,
                          const float* __restrict__ bl2,
                          float* __restrict__ out) {
    const int tid  = threadIdx.x;
    const int w    = tid >> 6;        // wave: unit tile [16w,16w+16)
    const int lane = tid & 63;
    const int q    = lane >> 4;       // MFMA quad
    const int mn   = lane & 15;       // B/C column
    const int row  = mn & 3;          // batch row within block
    const bool sb0 = (mn >> 2) & 1;   // rsel bit0
    const bool sb1 = (mn >> 3) & 1;   // rsel bit1
    const int u_own = 16 * w + 4 * q + (mn >> 2);  // this lane's hidden unit
    const int b0   = blockIdx.x * 4;

    __shared__ __align__(16) __bf16 hsh[2][4][96];  // row stride 192B: 2-way banks
    __shared__ int   toklds[Tt][4];                 // transposed: uniform-t read
    __shared__ float h2s[4][64];
    __shared__ float ys[4][128];

    float c = 0.0f, selh = 0.0f, selc = 0.0f;
    const f32x4 zero4 = {0.0f, 0.0f, 0.0f, 0.0f};

    for (int phase = 0; phase < 2; ++phase) {
        const float* tab  = phase ? tab2 : tab1;
        const float* Whh  = phase ? Whh2 : Whh1;
        const int*   sent = phase ? s2 : s1;
        const int*   lenp = phase ? len2 : len1;

        // stage tokens transposed (coalesced reads; one-time)
        for (int i = tid; i < 4 * Tt; i += 256)
            toklds[i & 255][i >> 8] = sent[(size_t)(b0 + (i >> 8)) * Tt + (i & 255)];

        // A fragments: m-tile k (gate type) covers gates 64k+16w+0..15
        b16x8 af[8];
#pragma unroll
        for (int k = 0; k < 4; ++k) {
            const int gate = 64 * k + 16 * w + mn;
#pragma unroll
            for (int kh = 0; kh < 2; ++kh) {
                const float* ar = Whh + (size_t)gate * Hh + kh * 32 + q * 8;
                const float4 f0 = *(const float4*)ar;
                const float4 f1 = *(const float4*)(ar + 4);
                b16x8 a;
                a[0] = (__bf16)f0.x; a[1] = (__bf16)f0.y;
                a[2] = (__bf16)f0.z; a[3] = (__bf16)f0.w;
                a[4] = (__bf16)f1.x; a[5] = (__bf16)f1.y;
                a[6] = (__bf16)f1.z; a[7] = (__bf16)f1.w;
                af[2 * k + kh] = a;
            }
        }

        const int mi = lenp[(size_t)(b0 + row) * Hh + u_own];

        // seed h/c (zeros phase 0, gathered state phase 1) into buffer 0
        const float h0f = phase ? selh : 0.0f;
        c = phase ? selc : 0.0f;
        hsh[0][row][u_own] = (__bf16)h0f;
        selh = 0.0f; selc = 0.0f;
        __syncthreads();

        // xw prefetch, distance 4: one float4 = all 4 gate xw of (token, u_own)
        const float* tu = tab + 4 * u_own;
        f32x4 Sa, Sb, Sc, Sd;
        auto prime = [&](int t, f32x4& S) {
            S = *(const f32x4*)(tu + (size_t)toklds[t][row] * 256);
        };
        prime(0, Sa); prime(1, Sb); prime(2, Sc); prime(3, Sd);

        // select acc element rsel (2-bit, runtime) with static element indices
        auto pick = [&](const f32x4& a) -> float {
            const float e01 = sb0 ? a[1] : a[0];
            const float e23 = sb0 ? a[3] : a[2];
            return sb1 ? e23 : e01;
        };

        auto step = [&](int t, f32x4& S, int rb, int wb) {
            // B frags: 4x column-duplicated rows (broadcast read = free)
            const b16x8 bf0 = *(const b16x8*)&hsh[rb][row][q * 8];
            const b16x8 bf1 = *(const b16x8*)&hsh[rb][row][32 + q * 8];
            const int tnext = (t + 4 < Tt) ? t + 4 : Tt - 1;
            const int tk = toklds[tnext][row];

            // order g,i,f,o: tanh(gG) is the longest dependent chain
            f32x4 aG = __builtin_amdgcn_mfma_f32_16x16x32_bf16(af[4], bf0, zero4, 0, 0, 0);
            aG = __builtin_amdgcn_mfma_f32_16x16x32_bf16(af[5], bf1, aG, 0, 0, 0);
            f32x4 aI = __builtin_amdgcn_mfma_f32_16x16x32_bf16(af[0], bf0, zero4, 0, 0, 0);
            aI = __builtin_amdgcn_mfma_f32_16x16x32_bf16(af[1], bf1, aI, 0, 0, 0);
            f32x4 aF = __builtin_amdgcn_mfma_f32_16x16x32_bf16(af[2], bf0, zero4, 0, 0, 0);
            aF = __builtin_amdgcn_mfma_f32_16x16x32_bf16(af[3], bf1, aF, 0, 0, 0);
            f32x4 aO = __builtin_amdgcn_mfma_f32_16x16x32_bf16(af[6], bf0, zero4, 0, 0, 0);
            aO = __builtin_amdgcn_mfma_f32_16x16x32_bf16(af[7], bf1, aO, 0, 0, 0);

            const float gG = pick(aG) + S[2];
            const float gI = pick(aI) + S[0];
            const float gF = pick(aF) + S[1];
            const float gO = pick(aO) + S[3];
            // refill S for t+4 (WAR on S keeps issue after the adds above)
            S = *(const f32x4*)(tu + (size_t)tk * 256);

            const float gv = ftanh(gG);
            const float iv = fsig(gI);
            const float fv = fsig(gF);
            const float ov = fsig(gO);
            c = fv * c + iv * gv;
            const float hv = ov * ftanh(c);
            hsh[wb][row][u_own] = (__bf16)hv;
            if (t == mi) { selh = hv; selc = c; }
            barrier_novm();   // ONE barrier/step; global prefetch stays in flight
        };

        for (int t = 0; t < Tt; t += 4) {
            step(t,     Sa, 0, 1);
            step(t + 1, Sb, 1, 0);
            step(t + 2, Sc, 0, 1);
            step(t + 3, Sd, 1, 0);
        }
    }

    // ---------------- epilogue MLP on the 4 gathered rows -------------------
    h2s[row][u_own] = selh;
    __syncthreads();
#pragma unroll
    for (int p = 0; p < 2; ++p) {
        const int idx = tid + 256 * p;        // 512 (row, neuron) tasks
        const int rr = idx >> 7, n = idx & 127;
        float a = bl1[n];
        const float* wl = Wl1 + n * 64;
#pragma unroll 8
        for (int k = 0; k < 64; ++k) a += h2s[rr][k] * wl[k];
        ys[rr][n] = ftanh(a);
    }
    __syncthreads();
    if (tid < 16) {
        const int rr = tid >> 2, o = tid & 3;
        float a = bl2[o];
        const float* wl = Wl2 + o * 128;
#pragma unroll 8
        for (int k = 0; k < 128; ++k) a += ys[rr][k] * wl[k];
        out[(size_t)(b0 + rr) * 4 + o] = a;
    }
}

// ---------------------------------------------------------------------------
extern "C" void kernel_launch(void* const* d_in, const int* in_sizes, int n_in,
                              void* d_out, int out_size, void* d_ws, size_t ws_size,
                              hipStream_t stream) {
    const int*   s1   = (const int*)d_in[0];
    const int*   s2   = (const int*)d_in[1];
    const int*   l1   = (const int*)d_in[2];
    const int*   l2   = (const int*)d_in[3];
    // d_in[4], d_in[5] (s1_s, s2_s) unused by the reference
    const float* emb  = (const float*)d_in[6];
    const float* Wih1 = (const float*)d_in[7];
    const float* Whh1 = (const float*)d_in[8];
    const float* bih1 = (const float*)d_in[9];
    const float* bhh1 = (const float*)d_in[10];
    const float* Wih2 = (const float*)d_in[11];
    const float* Whh2 = (const float*)d_in[12];
    const float* bih2 = (const float*)d_in[13];
    const float* bhh2 = (const float*)d_in[14];
    const float* Wl1  = (const float*)d_in[15];
    const float* bl1  = (const float*)d_in[16];
    const float* Wl2  = (const float*)d_in[17];
    const float* bl2  = (const float*)d_in[18];
    float* out = (float*)d_out;

    float* tab1 = (float*)d_ws;                       // [V,256] fp32, unit-major
    float* tab2 = tab1 + (size_t)Vv * 256;            // [V,256] fp32  (65.6 MB)

    dim3 grid((Vv + MB - 1) / MB, 2);
    build_tables<<<grid, 256, 0, stream>>>(emb, Wih1, bih1, bhh1,
                                           Wih2, bih2, bhh2, tab1, tab2);
    lstm_main<<<Bsz / 4, 256, 0, stream>>>(s1, s2, l1, l2, tab1, tab2,
                                           Whh1, Whh2, Wl1, bl1, Wl2, bl2, out);
}